// Round 17
// baseline (890.190 us; speedup 1.0000x reference)
//
#include <hip/hip_runtime.h>

typedef _Float16 f16;
typedef _Float16 f16x8 __attribute__((ext_vector_type(8)));
typedef _Float16 f16x4 __attribute__((ext_vector_type(4)));
typedef float    f32x4 __attribute__((ext_vector_type(4)));

#define B_SZ   2048
#define NCH    256
#define L0_    127
#define L1_    125
#define L2_    123
#define L3_    121
#define F1_    512
#define FCK    30976
#define KCH    968         // 30976 / 32 k-chunks
#define SPLIT  22          // split-K for FC1: 968 = 22 * 44 exactly
#define KPS    44          // 32-chunks per split = 22 BK-64 steps
#define NS_FC  22

// async global->LDS, 16B per lane; dest = wave-uniform base + lane*16
__device__ __forceinline__ void gl16(const f16* g, f16* l) {
    __builtin_amdgcn_global_load_lds(
        (const __attribute__((address_space(1))) void*)g,
        (__attribute__((address_space(3))) void*)l, 16, 0, 0);
}

// ---------------------------------------------------------------------------
// merged weight prep, CHUNK-MAJOR [ks32][co][32] (coalesced staging):
// wpw: 4 chunks (K=128: [wp1 | wp0]); wct1..3: 24 chunks (kt = k*256+ci)
// ---------------------------------------------------------------------------
__global__ __launch_bounds__(256) void prep_w(const float* __restrict__ Wp,
                                              const float* __restrict__ W1,
                                              const float* __restrict__ W2,
                                              const float* __restrict__ W3,
                                              f16* __restrict__ wpw,
                                              f16* __restrict__ wct1,
                                              f16* __restrict__ wct2,
                                              f16* __restrict__ wct3) {
    int g = blockIdx.x;
    if (g < 128) {
        int idx = g * 256 + threadIdx.x;        // [ck][co][w5]
        int ck = idx >> 13, co = (idx >> 5) & 255, w5 = idx & 31;
        int j = ck * 32 + w5;                   // ci 0..127
        float v = (j < 64) ? Wp[co * 128 + j * 2 + 1]
                           : Wp[co * 128 + (j - 64) * 2];
        wpw[idx] = (f16)v;
        return;
    }
    int g2 = g - 128;
    const float* W = (g2 < 768) ? W1 : (g2 < 1536) ? W2 : W3;
    f16* dst = (g2 < 768) ? wct1 : (g2 < 1536) ? wct2 : wct3;
    int idx = (g2 % 768) * 256 + threadIdx.x;   // [ck][co][w5]
    int ck = idx >> 13, co = (idx >> 5) & 255, w5 = idx & 31;
    int kt = ck * 32 + w5;
    int k = kt >> 8, ci = kt & 255;
    dst[idx] = (f16)W[((size_t)co * NCH + ci) * 3 + k];
}

__global__ __launch_bounds__(256) void prep_wf1k(const float* __restrict__ Wf1,
                                                 f16* __restrict__ wf1h) {
    __shared__ f16 t[NCH * 122];
    const int f = blockIdx.x, tid = threadIdx.x;
    const float* src = Wf1 + (size_t)f * FCK;
    for (int idx = tid; idx < FCK; idx += 256) {
        int co = idx / 121, l = idx - co * 121;
        t[co * 122 + l] = (f16)src[idx];
    }
    __syncthreads();
    f16* dst = wf1h + (size_t)f * FCK;
    for (int idx = tid; idx < FCK; idx += 256) {
        int l = idx >> 8, co = idx & 255;
        dst[idx] = t[co * 122 + l];
    }
}

// ---------------------------------------------------------------------------
// Conv / pointwise, BK=64, 8 WAVES = 2 waves/SIMD (the R17 change).
// Block = one b, 512 thr = 8 waves (2 l-halves x 4 co-quarters), wave tile
// 64l x 64co.  A: [SROWS][CIN] LDS, XOR-swizzled, staged once.  B: 2-buffer
// dbuf (16K f16 each) via gl16, chunk-major source.  One barrier per step
// (R16 protocol): stage(s+1)->cur^1; reads of cur; 2x16 MFMA; vmcnt(0);
// barrier.  2 waves/SIMD let one wave's MFMAs hide the other's reads.
// ---------------------------------------------------------------------------
template <int NS, int CSTEPS, int UPR, int CIN, int SROWS, int LIN,
          int LOUT, bool ISPW>
__global__ __launch_bounds__(512, 1) void convk(const f16* __restrict__ in,
                                                long in_bstride,
                                                const float* __restrict__ xin,
                                                const f16* __restrict__ wt,
                                                const float* __restrict__ bias,
                                                f16* __restrict__ out) {
    constexpr int BUFF = 16384;                  // f16 per B buffer (2 chunks)
    __shared__ f16 ins[SROWS * CIN];
    __shared__ f16 wlds[2 * BUFF];

    const int b    = blockIdx.x;
    const int tid  = threadIdx.x;
    const int lane = tid & 63, w = tid >> 6;     // 8 waves
    const int wl0  = (w >> 2) * 64;              // l half
    const int wc0  = (w & 3) * 64;               // co quarter
    const int lr   = lane & 15, lh = lane >> 4;

    // stage BK=64 pair s2 (chunks 2*s2, 2*s2+1): 4 gl16/thread, coalesced
    auto stageB = [&](int s2, int buf) {
        const f16* src0 = wt + (size_t)(2 * s2) * 8192;
#pragma unroll
        for (int j = 0; j < 4; ++j) {
            int u = j * 512 + w * 64 + lane;     // 16B unit, 0..2047
            int row = u >> 2, cu = u & 3;        // row 0..511 spans both chunks
            int cs = cu ^ ((row >> 2) & 3);
            gl16(src0 + row * 32 + cs * 8,
                 wlds + buf * BUFF + (size_t)(j * 512 + w * 64) * 8);
        }
    };

    stageB(0, 0);
    // stage A tile, XOR-swizzled (16B units, unit ^= row&7)
    if (ISPW) {
        const float* xr = xin + (size_t)b * 8192;
        for (int u = tid; u < SROWS * UPR; u += 512) {
            int r = u / UPR, sl = u % UPR;
            int off = (sl < 8) ? ((r + 1 < 128 ? (r + 1) * 64 : 127 * 64) + sl * 8)
                               : (sl - 8) * 8;   // x0 block
            float4 v0 = *(const float4*)(xr + off);
            float4 v1 = *(const float4*)(xr + off + 4);
            f16x8 h = { (f16)v0.x, (f16)v0.y, (f16)v0.z, (f16)v0.w,
                        (f16)v1.x, (f16)v1.y, (f16)v1.z, (f16)v1.w };
            *(f16x8*)(ins + r * CIN + ((sl ^ (r & 7)) << 3)) = h;
        }
    } else {
        const f16* inb = in + (size_t)b * in_bstride;
        for (int u = tid; u < SROWS * UPR; u += 512) {
            int r = u / UPR, sl = u % UPR;
            int sr = (r < LIN) ? r : (LIN - 1);
            *(f16x8*)(ins + r * CIN + ((sl ^ (r & 7)) << 3)) =
                *(const f16x8*)(inb + (size_t)sr * NCH + sl * 8);
        }
    }
    __syncthreads();                             // drains all prologue vmem

    f32x4 acc[4][4];
#pragma unroll
    for (int m = 0; m < 4; ++m)
#pragma unroll
        for (int n = 0; n < 4; ++n) acc[m][n] = (f32x4){0.f, 0.f, 0.f, 0.f};

#pragma unroll 1
    for (int s = 0; s < NS; ++s) {
        const int cur = s & 1;
        if (s + 1 < NS) stageB(s + 1, cur ^ 1);
        __builtin_amdgcn_sched_barrier(0);
#pragma unroll
        for (int kk = 0; kk < 2; ++kk) {
            const int ks32 = 2 * s + kk;
            const int k = ks32 / CSTEPS, cb = (ks32 % CSTEPS) * 4;
            f16x8 a[4], bf[4];
#pragma unroll
            for (int m = 0; m < 4; ++m) {
                const int r_ = wl0 + 16 * m + lr + k;
                a[m] = *(const f16x8*)(ins + r_ * CIN
                                       + (((cb + lh) ^ (r_ & 7)) << 3));
            }
#pragma unroll
            for (int n = 0; n < 4; ++n) {
                const int co = wc0 + 16 * n + lr;
                bf[n] = *(const f16x8*)(wlds + cur * BUFF + kk * 8192
                                        + (co * 4 + (lh ^ ((co >> 2) & 3))) * 8);
            }
            __builtin_amdgcn_s_setprio(1);
#pragma unroll
            for (int n = 0; n < 4; ++n)
#pragma unroll
                for (int m = 0; m < 4; ++m)
                    acc[m][n] = __builtin_amdgcn_mfma_f32_16x16x32_f16(
                        a[m], bf[n], acc[m][n], 0, 0, 0);
            __builtin_amdgcn_s_setprio(0);
        }
        __builtin_amdgcn_sched_barrier(0);
        asm volatile("s_waitcnt vmcnt(0)" ::: "memory");
        __builtin_amdgcn_sched_barrier(0);
        __builtin_amdgcn_s_barrier();
    }

    // epilogue: +bias, relu, fp16 store to [b][l][256]
    f16* ob = out + (size_t)b * LOUT * NCH;
#pragma unroll
    for (int n = 0; n < 4; ++n) {
        const int co = wc0 + 16 * n + lr;
        const float e = bias[co];
#pragma unroll
        for (int m = 0; m < 4; ++m)
#pragma unroll
            for (int r = 0; r < 4; ++r) {
                const int l = wl0 + 16 * m + lh * 4 + r;
                if (l < LOUT) {
                    float v = fmaxf(acc[m][n][r] + e, 0.f);
                    ob[(size_t)l * NCH + co] = (f16)v;
                }
            }
    }
}

// ---------------------------------------------------------------------------
// FC1, BK=64 (R16 verbatim): tile 128b x 256f, 512 thr = 8 waves.
// ---------------------------------------------------------------------------
__global__ __launch_bounds__(512, 1) void fc1k(const f16* __restrict__ A,
                                               const f16* __restrict__ Bw,
                                               float* __restrict__ part,
                                               int CB) {
    __shared__ f16 Asl[2 * 8192];                // 2 x (128b x 64k)
    __shared__ f16 Bsl[2 * 16384];               // 2 x (256f x 64k)
    const int m0 = blockIdx.x * 128, n0 = blockIdx.y * 256, sp = blockIdx.z;
    const int tid  = threadIdx.x;
    const int lane = tid & 63, w = tid >> 6;
    const int wb0  = (w >> 2) * 64, wf0 = (w & 3) * 64;
    const int lr   = lane & 15, lh = lane >> 4;
    const int ck0  = sp * KPS;

    auto stage = [&](int s2, int buf) {
        const int k0 = (ck0 + 2 * s2) * 32;      // f16 col base, 64 wide
#pragma unroll
        for (int j = 0; j < 2; ++j) {            // A: 1024 units
            int u = j * 512 + tid;
            int row = u >> 3, cu = u & 7;
            int cs = cu ^ (row & 7);
            gl16(A + (size_t)(m0 + row) * FCK + k0 + cs * 8,
                 Asl + buf * 8192 + (size_t)(j * 512 + w * 64) * 8);
        }
#pragma unroll
        for (int j = 0; j < 4; ++j) {            // B: 2048 units
            int u = j * 512 + tid;
            int row = u >> 3, cu = u & 7;
            int cs = cu ^ (row & 7);
            gl16(Bw + (size_t)(n0 + row) * FCK + k0 + cs * 8,
                 Bsl + buf * 16384 + (size_t)(j * 512 + w * 64) * 8);
        }
    };

    f32x4 acc[4][4];
#pragma unroll
    for (int m = 0; m < 4; ++m)
#pragma unroll
        for (int n = 0; n < 4; ++n) acc[m][n] = (f32x4){0.f, 0.f, 0.f, 0.f};

    stage(0, 0);
    __syncthreads();

#pragma unroll 1
    for (int s = 0; s < NS_FC; ++s) {
        const int cur = s & 1;
        if (s + 1 < NS_FC) stage(s + 1, cur ^ 1);
        __builtin_amdgcn_sched_barrier(0);
#pragma unroll
        for (int kk = 0; kk < 2; ++kk) {
            f16x8 a[4], bf[4];
#pragma unroll
            for (int m = 0; m < 4; ++m) {
                const int row = wb0 + 16 * m + lr;
                const int un = (kk * 4 + lh) ^ (row & 7);
                a[m] = *(const f16x8*)(Asl + cur * 8192 + row * 64 + un * 8);
            }
#pragma unroll
            for (int n = 0; n < 4; ++n) {
                const int row = wf0 + 16 * n + lr;
                const int un = (kk * 4 + lh) ^ (row & 7);
                bf[n] = *(const f16x8*)(Bsl + cur * 16384 + row * 64 + un * 8);
            }
            __builtin_amdgcn_s_setprio(1);
#pragma unroll
            for (int m = 0; m < 4; ++m)
#pragma unroll
                for (int n = 0; n < 4; ++n)
                    acc[m][n] = __builtin_amdgcn_mfma_f32_16x16x32_f16(
                        a[m], bf[n], acc[m][n], 0, 0, 0);
            __builtin_amdgcn_s_setprio(0);
        }
        __builtin_amdgcn_sched_barrier(0);
        asm volatile("s_waitcnt vmcnt(0)" ::: "memory");
        __builtin_amdgcn_sched_barrier(0);
        __builtin_amdgcn_s_barrier();
    }

#pragma unroll
    for (int m = 0; m < 4; ++m)
#pragma unroll
        for (int n = 0; n < 4; ++n)
#pragma unroll
            for (int r = 0; r < 4; ++r) {
                const int bl = m0 + wb0 + 16 * m + lh * 4 + r;
                const int f  = n0 + wf0 + 16 * n + lr;
                part[((size_t)sp * CB + bl) * F1_ + f] = acc[m][n][r];
            }
}

// ---------------------------------------------------------------------------
// fused reduce + fc2: out[b] = bf2 + relu(bf1 + sum_sp part)[.] . Wf2
// ---------------------------------------------------------------------------
__global__ __launch_bounds__(512) void fcout(const float* __restrict__ part,
                                             const float* __restrict__ bf1,
                                             const float* __restrict__ Wf2,
                                             const float* __restrict__ bf2,
                                             float* __restrict__ out,
                                             int CB) {
    __shared__ float red[8];
    const int m = blockIdx.x;
    const int f = threadIdx.x;
    float s = bf1[f];
#pragma unroll
    for (int sp = 0; sp < SPLIT; ++sp)
        s += part[((size_t)sp * CB + m) * F1_ + f];
    float p = fmaxf(s, 0.f) * Wf2[f];
#pragma unroll
    for (int o = 32; o > 0; o >>= 1) p += __shfl_xor(p, o);
    if ((f & 63) == 0) red[f >> 6] = p;
    __syncthreads();
    if (f < 8) {
        float v = red[f];
        v += __shfl_xor(v, 1);
        v += __shfl_xor(v, 2);
        v += __shfl_xor(v, 4);
        if (f == 0) out[m] = v + bf2[0];
    }
}

// ---------------------------------------------------------------------------
extern "C" void kernel_launch(void* const* d_in, const int* in_sizes, int n_in,
                              void* d_out, int out_size, void* d_ws, size_t ws_size,
                              hipStream_t stream) {
    const float* x   = (const float*)d_in[0];
    const float* Wp  = (const float*)d_in[1];
    const float* bp  = (const float*)d_in[2];
    const float* W1  = (const float*)d_in[3];
    const float* b1  = (const float*)d_in[4];
    const float* W2  = (const float*)d_in[5];
    const float* b2  = (const float*)d_in[6];
    const float* W3  = (const float*)d_in[7];
    const float* b3  = (const float*)d_in[8];
    const float* Wf1 = (const float*)d_in[9];
    const float* bf1 = (const float*)d_in[10];
    const float* Wf2 = (const float*)d_in[11];
    const float* bf2 = (const float*)d_in[12];
    float* out = (float*)d_out;

    // ---- workspace layout ----------------------------------------------
    char* base = (char*)d_ws;
    size_t off = 0;
    auto alloc = [&](size_t bytes) {
        size_t o = off; off = (off + bytes + 255) & ~(size_t)255; return o;
    };
    const size_t o_wpw  = alloc((size_t)NCH * 128 * 2);
    const size_t o_wct1 = alloc((size_t)NCH * 768 * 2);
    const size_t o_wct2 = alloc((size_t)NCH * 768 * 2);
    const size_t o_wct3 = alloc((size_t)NCH * 768 * 2);
    const size_t o_wf1h = alloc((size_t)F1_ * FCK * 2);
    const size_t fixed  = off;

    int CB = 0;
    const int cand[5] = {2048, 1024, 512, 256, 128};
    for (int i = 0; i < 5; ++i) {
        size_t c = (size_t)cand[i];
        size_t need = fixed
            + (((size_t)SPLIT * c * F1_ * 4 + 255) & ~(size_t)255)   // part
            + ((c * (size_t)L0_ * NCH * 2 + 255) & ~(size_t)255)     // buf0
            + ((c * (size_t)L1_ * NCH * 2 + 255) & ~(size_t)255);    // buf1
        if (need <= ws_size) { CB = cand[i]; break; }
    }
    if (CB == 0) return;
    const int nchunk = B_SZ / CB;

    const size_t o_part = alloc((size_t)SPLIT * CB * F1_ * 4);
    const size_t o_buf0 = alloc((size_t)CB * L0_ * NCH * 2);
    const size_t o_buf1 = alloc((size_t)CB * L1_ * NCH * 2);

    f16*   wpw  = (f16*)(base + o_wpw);
    f16*   wct1 = (f16*)(base + o_wct1);
    f16*   wct2 = (f16*)(base + o_wct2);
    f16*   wct3 = (f16*)(base + o_wct3);
    f16*   wf1h = (f16*)(base + o_wf1h);
    float* part = (float*)(base + o_part);
    f16*   buf0 = (f16*)(base + o_buf0);
    f16*   buf1 = (f16*)(base + o_buf1);

    // ---- preps ---------------------------------------------------------
    prep_w<<<2432, 256, 0, stream>>>(Wp, W1, W2, W3, wpw, wct1, wct2, wct3);
    prep_wf1k<<<F1_, 256, 0, stream>>>(Wf1, wf1h);

    // ---- chunked pipeline ----------------------------------------------
    for (int c = 0; c < nchunk; ++c) {
        const size_t b0 = (size_t)c * CB;
        // pointwise as K=128 GEMM (2 BK-64 steps), fp32 x staged in-kernel
        convk<2, 4, 16, 128, 128, 128, L0_, true><<<CB, 512, 0, stream>>>(
            nullptr, 0, x + b0 * 8192, wpw, bp, buf0);
        convk<12, 8, 32, 256, 130, L0_, L1_, false><<<CB, 512, 0, stream>>>(
            buf0, (long)L0_ * NCH, nullptr, wct1, b1, buf1);
        convk<12, 8, 32, 256, 130, L1_, L2_, false><<<CB, 512, 0, stream>>>(
            buf1, (long)L1_ * NCH, nullptr, wct2, b2, buf0);
        convk<12, 8, 32, 256, 130, L2_, L3_, false><<<CB, 512, 0, stream>>>(
            buf0, (long)L2_ * NCH, nullptr, wct3, b3, buf1);
        // conv3 output [l][co] IS the FC1 A layout (wf1h K-permuted at prep)
        fc1k<<<dim3(CB / 128, 2, SPLIT), 512, 0, stream>>>(buf1, wf1h, part, CB);
        fcout<<<CB, 512, 0, stream>>>(part, bf1, Wf2, bf2, out + b0, CB);
    }
}

// Round 18
// 649.436 us; speedup vs baseline: 1.3707x; 1.3707x over previous
//
#include <hip/hip_runtime.h>

typedef _Float16 f16;
typedef _Float16 f16x8 __attribute__((ext_vector_type(8)));
typedef _Float16 f16x4 __attribute__((ext_vector_type(4)));
typedef float    f32x4 __attribute__((ext_vector_type(4)));

#define B_SZ   2048
#define NCH    256
#define L0_    127
#define L1_    125
#define L2_    123
#define L3_    121
#define F1_    512
#define FCK    30976
#define KCH    968         // 30976 / 32 k-chunks
#define SPLIT  22          // split-K for FC1: 968 = 22 * 44 exactly
#define KPS    44          // 32-chunks per split = 22 BK-64 steps
#define NS_FC  22
#define BUFF   16384       // f16 per B buffer (2 chunks)

// async global->LDS, 16B per lane; dest = wave-uniform base + lane*16
__device__ __forceinline__ void gl16(const f16* g, f16* l) {
    __builtin_amdgcn_global_load_lds(
        (const __attribute__((address_space(1))) void*)g,
        (__attribute__((address_space(3))) void*)l, 16, 0, 0);
}

// ---------------------------------------------------------------------------
// merged weight prep, CHUNK-MAJOR [ks32][co][32]:
// wpw: 4 chunks (K=128: [wp1 | wp0]); wct1..3: 24 chunks (kt = k*256+ci)
// ---------------------------------------------------------------------------
__global__ __launch_bounds__(256) void prep_w(const float* __restrict__ Wp,
                                              const float* __restrict__ W1,
                                              const float* __restrict__ W2,
                                              const float* __restrict__ W3,
                                              f16* __restrict__ wpw,
                                              f16* __restrict__ wct1,
                                              f16* __restrict__ wct2,
                                              f16* __restrict__ wct3) {
    int g = blockIdx.x;
    if (g < 128) {
        int idx = g * 256 + threadIdx.x;        // [ck][co][w5]
        int ck = idx >> 13, co = (idx >> 5) & 255, w5 = idx & 31;
        int j = ck * 32 + w5;                   // ci 0..127
        float v = (j < 64) ? Wp[co * 128 + j * 2 + 1]
                           : Wp[co * 128 + (j - 64) * 2];
        wpw[idx] = (f16)v;
        return;
    }
    int g2 = g - 128;
    const float* W = (g2 < 768) ? W1 : (g2 < 1536) ? W2 : W3;
    f16* dst = (g2 < 768) ? wct1 : (g2 < 1536) ? wct2 : wct3;
    int idx = (g2 % 768) * 256 + threadIdx.x;   // [ck][co][w5]
    int ck = idx >> 13, co = (idx >> 5) & 255, w5 = idx & 31;
    int kt = ck * 32 + w5;
    int k = kt >> 8, ci = kt & 255;
    dst[idx] = (f16)W[((size_t)co * NCH + ci) * 3 + k];
}

__global__ __launch_bounds__(256) void prep_wf1k(const float* __restrict__ Wf1,
                                                 f16* __restrict__ wf1h) {
    __shared__ f16 t[NCH * 122];
    const int f = blockIdx.x, tid = threadIdx.x;
    const float* src = Wf1 + (size_t)f * FCK;
    for (int idx = tid; idx < FCK; idx += 256) {
        int co = idx / 121, l = idx - co * 121;
        t[co * 122 + l] = (f16)src[idx];
    }
    __syncthreads();
    f16* dst = wf1h + (size_t)f * FCK;
    for (int idx = tid; idx < FCK; idx += 256) {
        int l = idx >> 8, co = idx & 255;
        dst[idx] = t[co * 122 + l];
    }
}

// ---------------------------------------------------------------------------
// FUSED pointwise + conv1 + conv2 + conv3 (the R18 change).
// Block = one b, 256 thr = 4 waves (co quarters), wave tile 128l x 64co.
// Activation tile [130][256] resident in LDS (XOR-swizzled), updated
// IN-PLACE at each layer boundary (K-loop reads all complete at the
// end-of-loop barrier; epilogue then overwrites rows 0..LOUT-1; rows
// beyond LOUT keep stale finite data, reaching only discarded acc rows).
// B: 2x16K-f16 dbuf via gl16, chunk-major, R16's one-barrier-per-step loop.
// ---------------------------------------------------------------------------
#define STAGEB(WT, S2, BUF)                                                   \
  {                                                                           \
    const f16* src0_ = (WT) + (size_t)(2 * (S2)) * 8192;                      \
    _Pragma("unroll")                                                         \
    for (int j = 0; j < 8; ++j) {                                             \
        int u_ = j * 256 + w * 64 + lane;                                     \
        int row_ = u_ >> 2, cu_ = u_ & 3;                                     \
        int cs_ = cu_ ^ ((row_ >> 2) & 3);                                    \
        gl16(src0_ + row_ * 32 + cs_ * 8,                                     \
             wlds + (BUF) * BUFF + (size_t)(j * 256 + w * 64) * 8);           \
    }                                                                         \
  }

#define GEMM_LAYER(WT, NS, CSTEPS)                                            \
  _Pragma("unroll")                                                           \
  for (int m = 0; m < 8; ++m)                                                 \
    _Pragma("unroll")                                                         \
    for (int n = 0; n < 4; ++n) acc[m][n] = (f32x4){0.f, 0.f, 0.f, 0.f};      \
  _Pragma("unroll 1")                                                         \
  for (int s = 0; s < (NS); ++s) {                                            \
    const int cur = s & 1;                                                    \
    if (s + 1 < (NS)) STAGEB(WT, s + 1, cur ^ 1)                              \
    __builtin_amdgcn_sched_barrier(0);                                        \
    _Pragma("unroll")                                                         \
    for (int kk = 0; kk < 2; ++kk) {                                          \
      const int ks32 = 2 * s + kk;                                            \
      const int k = ks32 / (CSTEPS), cb = (ks32 % (CSTEPS)) * 4;              \
      f16x8 a[8], bf[4];                                                      \
      _Pragma("unroll")                                                       \
      for (int m = 0; m < 8; ++m) {                                           \
        const int r_ = 16 * m + lr + k;                                       \
        a[m] = *(const f16x8*)(ins + r_ * 256 + (((cb + lh) ^ (r_ & 7)) << 3)); \
      }                                                                       \
      _Pragma("unroll")                                                       \
      for (int n = 0; n < 4; ++n) {                                           \
        const int co = wc0 + 16 * n + lr;                                     \
        bf[n] = *(const f16x8*)(wlds + cur * BUFF + kk * 8192                 \
                                + (co * 4 + (lh ^ ((co >> 2) & 3))) * 8);     \
      }                                                                       \
      __builtin_amdgcn_s_setprio(1);                                          \
      _Pragma("unroll")                                                       \
      for (int n = 0; n < 4; ++n)                                             \
        _Pragma("unroll")                                                     \
        for (int m = 0; m < 8; ++m)                                           \
          acc[m][n] = __builtin_amdgcn_mfma_f32_16x16x32_f16(a[m], bf[n],     \
                                                             acc[m][n], 0, 0, 0); \
      __builtin_amdgcn_s_setprio(0);                                          \
    }                                                                         \
    __builtin_amdgcn_sched_barrier(0);                                        \
    asm volatile("s_waitcnt vmcnt(0)" ::: "memory");                          \
    __builtin_amdgcn_sched_barrier(0);                                        \
    __builtin_amdgcn_s_barrier();                                             \
  }

// epilogue: acc -> activation tile (bias+relu, f16, XOR-swizzled), in place
#define EPI_LDS(BIAS, LOUT)                                                   \
  {                                                                           \
    _Pragma("unroll")                                                         \
    for (int n = 0; n < 4; ++n) {                                             \
      const int co = wc0 + 16 * n + lr;                                       \
      const float e = (BIAS)[co];                                             \
      const int sl = co >> 3, el = co & 7;                                    \
      _Pragma("unroll")                                                       \
      for (int m = 0; m < 8; ++m)                                             \
        _Pragma("unroll")                                                     \
        for (int r = 0; r < 4; ++r) {                                         \
          const int l = 16 * m + lh * 4 + r;                                  \
          if (l < (LOUT)) {                                                   \
            float v = fmaxf(acc[m][n][r] + e, 0.f);                           \
            ins[l * 256 + (((sl) ^ (l & 7)) << 3) + el] = (f16)v;             \
          }                                                                   \
        }                                                                     \
    }                                                                         \
  }

__global__ __launch_bounds__(256, 1) void fused_conv(
        const float* __restrict__ xin,
        const f16* __restrict__ wpw,  const float* __restrict__ bp,
        const f16* __restrict__ wct1, const float* __restrict__ b1,
        const f16* __restrict__ wct2, const float* __restrict__ b2,
        const f16* __restrict__ wct3, const float* __restrict__ b3,
        f16* __restrict__ h3out) {
    __shared__ f16 ins[130 * 256];
    __shared__ f16 wlds[2 * BUFF];

    const int b    = blockIdx.x;
    const int tid  = threadIdx.x;
    const int lane = tid & 63, w = tid >> 6;     // 4 waves
    const int wc0  = w * 64;                     // wave's 64-co quarter
    const int lr   = lane & 15, lh = lane >> 4;

    f32x4 acc[8][4];

    // prologue: stage pw B chunk 0, then x -> act tile (row r = [xr(r+1)|x0])
    STAGEB(wpw, 0, 0)
    {
        const float* xr = xin + (size_t)b * 8192;
        for (int u = tid; u < 130 * 16; u += 256) {
            int r = u >> 4, sl = u & 15;
            int off = (sl < 8)
                ? ((r + 1 < 128 ? (r + 1) * 64 : 127 * 64) + sl * 8)
                : (sl - 8) * 8;                  // x0 block
            float4 v0 = *(const float4*)(xr + off);
            float4 v1 = *(const float4*)(xr + off + 4);
            f16x8 h = { (f16)v0.x, (f16)v0.y, (f16)v0.z, (f16)v0.w,
                        (f16)v1.x, (f16)v1.y, (f16)v1.z, (f16)v1.w };
            *(f16x8*)(ins + r * 256 + ((sl ^ (r & 7)) << 3)) = h;
        }
    }
    __syncthreads();                             // drains stage + act writes

    // ---- pointwise (K=128, 2 BK-64 steps) ----
    GEMM_LAYER(wpw, 2, 4)
    STAGEB(wct1, 0, 0)
    EPI_LDS(bp, L0_)
    asm volatile("s_waitcnt vmcnt(0) lgkmcnt(0)" ::: "memory");
    __builtin_amdgcn_s_barrier();

    // ---- conv1 ----
    GEMM_LAYER(wct1, 12, 8)
    STAGEB(wct2, 0, 0)
    EPI_LDS(b1, L1_)
    asm volatile("s_waitcnt vmcnt(0) lgkmcnt(0)" ::: "memory");
    __builtin_amdgcn_s_barrier();

    // ---- conv2 ----
    GEMM_LAYER(wct2, 12, 8)
    STAGEB(wct3, 0, 0)
    EPI_LDS(b2, L2_)
    asm volatile("s_waitcnt vmcnt(0) lgkmcnt(0)" ::: "memory");
    __builtin_amdgcn_s_barrier();

    // ---- conv3 -> global h3 [l][co] (FC1-ready) ----
    GEMM_LAYER(wct3, 12, 8)
    {
        f16* ob = h3out + (size_t)b * L3_ * NCH;
#pragma unroll
        for (int n = 0; n < 4; ++n) {
            const int co = wc0 + 16 * n + lr;
            const float e = b3[co];
#pragma unroll
            for (int m = 0; m < 8; ++m)
#pragma unroll
                for (int r = 0; r < 4; ++r) {
                    const int l = 16 * m + lh * 4 + r;
                    if (l < L3_) {
                        float v = fmaxf(acc[m][n][r] + e, 0.f);
                        ob[(size_t)l * NCH + co] = (f16)v;
                    }
                }
        }
    }
}

// ---------------------------------------------------------------------------
// FC1, BK=64 (R16 verbatim): tile 128b x 256f, 512 thr = 8 waves.
// ---------------------------------------------------------------------------
__global__ __launch_bounds__(512, 1) void fc1k(const f16* __restrict__ A,
                                               const f16* __restrict__ Bw,
                                               float* __restrict__ part,
                                               int CB) {
    __shared__ f16 Asl[2 * 8192];                // 2 x (128b x 64k)
    __shared__ f16 Bsl[2 * 16384];               // 2 x (256f x 64k)
    const int m0 = blockIdx.x * 128, n0 = blockIdx.y * 256, sp = blockIdx.z;
    const int tid  = threadIdx.x;
    const int lane = tid & 63, w = tid >> 6;
    const int wb0  = (w >> 2) * 64, wf0 = (w & 3) * 64;
    const int lr   = lane & 15, lh = lane >> 4;
    const int ck0  = sp * KPS;

    auto stage = [&](int s2, int buf) {
        const int k0 = (ck0 + 2 * s2) * 32;      // f16 col base, 64 wide
#pragma unroll
        for (int j = 0; j < 2; ++j) {            // A: 1024 units
            int u = j * 512 + tid;
            int row = u >> 3, cu = u & 7;
            int cs = cu ^ (row & 7);
            gl16(A + (size_t)(m0 + row) * FCK + k0 + cs * 8,
                 Asl + buf * 8192 + (size_t)(j * 512 + w * 64) * 8);
        }
#pragma unroll
        for (int j = 0; j < 4; ++j) {            // B: 2048 units
            int u = j * 512 + tid;
            int row = u >> 3, cu = u & 7;
            int cs = cu ^ (row & 7);
            gl16(Bw + (size_t)(n0 + row) * FCK + k0 + cs * 8,
                 Bsl + buf * 16384 + (size_t)(j * 512 + w * 64) * 8);
        }
    };

    f32x4 acc[4][4];
#pragma unroll
    for (int m = 0; m < 4; ++m)
#pragma unroll
        for (int n = 0; n < 4; ++n) acc[m][n] = (f32x4){0.f, 0.f, 0.f, 0.f};

    stage(0, 0);
    __syncthreads();

#pragma unroll 1
    for (int s = 0; s < NS_FC; ++s) {
        const int cur = s & 1;
        if (s + 1 < NS_FC) stage(s + 1, cur ^ 1);
        __builtin_amdgcn_sched_barrier(0);
#pragma unroll
        for (int kk = 0; kk < 2; ++kk) {
            f16x8 a[4], bf[4];
#pragma unroll
            for (int m = 0; m < 4; ++m) {
                const int row = wb0 + 16 * m + lr;
                const int un = (kk * 4 + lh) ^ (row & 7);
                a[m] = *(const f16x8*)(Asl + cur * 8192 + row * 64 + un * 8);
            }
#pragma unroll
            for (int n = 0; n < 4; ++n) {
                const int row = wf0 + 16 * n + lr;
                const int un = (kk * 4 + lh) ^ (row & 7);
                bf[n] = *(const f16x8*)(Bsl + cur * 16384 + row * 64 + un * 8);
            }
            __builtin_amdgcn_s_setprio(1);
#pragma unroll
            for (int m = 0; m < 4; ++m)
#pragma unroll
                for (int n = 0; n < 4; ++n)
                    acc[m][n] = __builtin_amdgcn_mfma_f32_16x16x32_f16(
                        a[m], bf[n], acc[m][n], 0, 0, 0);
            __builtin_amdgcn_s_setprio(0);
        }
        __builtin_amdgcn_sched_barrier(0);
        asm volatile("s_waitcnt vmcnt(0)" ::: "memory");
        __builtin_amdgcn_sched_barrier(0);
        __builtin_amdgcn_s_barrier();
    }

#pragma unroll
    for (int m = 0; m < 4; ++m)
#pragma unroll
        for (int n = 0; n < 4; ++n)
#pragma unroll
            for (int r = 0; r < 4; ++r) {
                const int bl = m0 + wb0 + 16 * m + lh * 4 + r;
                const int f  = n0 + wf0 + 16 * n + lr;
                part[((size_t)sp * CB + bl) * F1_ + f] = acc[m][n][r];
            }
}

// ---------------------------------------------------------------------------
// fused reduce + fc2: out[b] = bf2 + relu(bf1 + sum_sp part)[.] . Wf2
// ---------------------------------------------------------------------------
__global__ __launch_bounds__(512) void fcout(const float* __restrict__ part,
                                             const float* __restrict__ bf1,
                                             const float* __restrict__ Wf2,
                                             const float* __restrict__ bf2,
                                             float* __restrict__ out,
                                             int CB) {
    __shared__ float red[8];
    const int m = blockIdx.x;
    const int f = threadIdx.x;
    float s = bf1[f];
#pragma unroll
    for (int sp = 0; sp < SPLIT; ++sp)
        s += part[((size_t)sp * CB + m) * F1_ + f];
    float p = fmaxf(s, 0.f) * Wf2[f];
#pragma unroll
    for (int o = 32; o > 0; o >>= 1) p += __shfl_xor(p, o);
    if ((f & 63) == 0) red[f >> 6] = p;
    __syncthreads();
    if (f < 8) {
        float v = red[f];
        v += __shfl_xor(v, 1);
        v += __shfl_xor(v, 2);
        v += __shfl_xor(v, 4);
        if (f == 0) out[m] = v + bf2[0];
    }
}

// ---------------------------------------------------------------------------
extern "C" void kernel_launch(void* const* d_in, const int* in_sizes, int n_in,
                              void* d_out, int out_size, void* d_ws, size_t ws_size,
                              hipStream_t stream) {
    const float* x   = (const float*)d_in[0];
    const float* Wp  = (const float*)d_in[1];
    const float* bp  = (const float*)d_in[2];
    const float* W1  = (const float*)d_in[3];
    const float* b1  = (const float*)d_in[4];
    const float* W2  = (const float*)d_in[5];
    const float* b2  = (const float*)d_in[6];
    const float* W3  = (const float*)d_in[7];
    const float* b3  = (const float*)d_in[8];
    const float* Wf1 = (const float*)d_in[9];
    const float* bf1 = (const float*)d_in[10];
    const float* Wf2 = (const float*)d_in[11];
    const float* bf2 = (const float*)d_in[12];
    float* out = (float*)d_out;

    // ---- workspace layout ----------------------------------------------
    char* base = (char*)d_ws;
    size_t off = 0;
    auto alloc = [&](size_t bytes) {
        size_t o = off; off = (off + bytes + 255) & ~(size_t)255; return o;
    };
    const size_t o_wpw  = alloc((size_t)NCH * 128 * 2);
    const size_t o_wct1 = alloc((size_t)NCH * 768 * 2);
    const size_t o_wct2 = alloc((size_t)NCH * 768 * 2);
    const size_t o_wct3 = alloc((size_t)NCH * 768 * 2);
    const size_t o_wf1h = alloc((size_t)F1_ * FCK * 2);
    const size_t fixed  = off;

    int CB = 0;
    const int cand[5] = {2048, 1024, 512, 256, 128};
    for (int i = 0; i < 5; ++i) {
        size_t c = (size_t)cand[i];
        size_t need = fixed
            + (((size_t)SPLIT * c * F1_ * 4 + 255) & ~(size_t)255)   // part
            + ((c * (size_t)L3_ * NCH * 2 + 255) & ~(size_t)255);    // h3
        if (need <= ws_size) { CB = cand[i]; break; }
    }
    if (CB == 0) return;
    const int nchunk = B_SZ / CB;

    const size_t o_part = alloc((size_t)SPLIT * CB * F1_ * 4);
    const size_t o_h3   = alloc((size_t)CB * L3_ * NCH * 2);

    f16*   wpw  = (f16*)(base + o_wpw);
    f16*   wct1 = (f16*)(base + o_wct1);
    f16*   wct2 = (f16*)(base + o_wct2);
    f16*   wct3 = (f16*)(base + o_wct3);
    f16*   wf1h = (f16*)(base + o_wf1h);
    float* part = (float*)(base + o_part);
    f16*   h3   = (f16*)(base + o_h3);

    // ---- preps ---------------------------------------------------------
    prep_w<<<2432, 256, 0, stream>>>(Wp, W1, W2, W3, wpw, wct1, wct2, wct3);
    prep_wf1k<<<F1_, 256, 0, stream>>>(Wf1, wf1h);

    // ---- chunked pipeline ----------------------------------------------
    for (int c = 0; c < nchunk; ++c) {
        const size_t b0 = (size_t)c * CB;
        fused_conv<<<CB, 256, 0, stream>>>(x + b0 * 8192,
                                           wpw, bp, wct1, b1, wct2, b2,
                                           wct3, b3, h3);
        fc1k<<<dim3(CB / 128, 2, SPLIT), 512, 0, stream>>>(h3, wf1h, part, CB);
        fcout<<<CB, 512, 0, stream>>>(part, bf1, Wf2, bf2, out + b0, CB);
    }
}